// Round 2
// 415.663 us; speedup vs baseline: 1.0345x; 1.0345x over previous
//
#include <hip/hip_runtime.h>
#include <hip/hip_bf16.h>

// Problem constants
#define BATCH 96
#define CH    96
#define SEQ   96
#define NHEAD 8
#define DK    96
#define DMODEL 768   // NHEAD*DK
#define GRP   8
#define EPSV  1e-5f

typedef __bf16 bf16x8 __attribute__((ext_vector_type(8)));
typedef float  f32x4  __attribute__((ext_vector_type(4)));
typedef unsigned short u16;

#define MFMA16(a, b, c) __builtin_amdgcn_mfma_f32_16x16x32_bf16((a), (b), (c), 0, 0, 0)

__device__ __forceinline__ u16 f2bf(float f) {
    union { float f; unsigned int u; } c; c.f = f;
    unsigned int u = c.u + 0x7fffu + ((c.u >> 16) & 1u);   // RNE
    return (u16)(u >> 16);
}

// ---------------------------------------------------------------------------
// 1) Prep: GroupNorm (blocks 0..767) + weight transpose/cast (blocks 768..3071)
//    gn: one block per (b,g), 128 threads x 9 elems (1152 per group).
//    wconv: seg 0..2: W (96,768)->WT (768,96); seg 3: Wo (768,96)->WoT (96,768)
// ---------------------------------------------------------------------------
__global__ __launch_bounds__(128) void prep_kernel(
        const float* __restrict__ x, const float* __restrict__ gamma,
        const float* __restrict__ beta,
        const float* __restrict__ Wq, const float* __restrict__ Wk,
        const float* __restrict__ Wv, const float* __restrict__ Wo,
        float* __restrict__ xn, u16* __restrict__ xn_bf,
        u16* __restrict__ WqT, u16* __restrict__ WkT,
        u16* __restrict__ WvT, u16* __restrict__ WoT) {
    if (blockIdx.x < 768) {
        int bg = blockIdx.x;
        int b = bg >> 3, g = bg & 7;
        const float* xp = x + b * 9216 + g * 1152;
        float vals[9];
        float s = 0.f, ss = 0.f;
        #pragma unroll
        for (int r = 0; r < 9; ++r) {
            float v = xp[threadIdx.x + 128 * r];
            vals[r] = v; s += v; ss += v * v;
        }
        #pragma unroll
        for (int off = 32; off > 0; off >>= 1) {
            s  += __shfl_down(s, off);
            ss += __shfl_down(ss, off);
        }
        __shared__ float red[4];
        if ((threadIdx.x & 63) == 0) {
            red[(threadIdx.x >> 6) * 2]     = s;
            red[(threadIdx.x >> 6) * 2 + 1] = ss;
        }
        __syncthreads();
        s = red[0] + red[2]; ss = red[1] + red[3];
        float mu   = s * (1.0f / 1152.0f);
        float var  = ss * (1.0f / 1152.0f) - mu * mu;
        float rsig = rsqrtf(var + EPSV);
        #pragma unroll
        for (int r = 0; r < 9; ++r) {
            int e = threadIdx.x + 128 * r;
            int c = g * 12 + e / 96;
            float v = (vals[r] - mu) * rsig * gamma[c] + beta[c];
            int idx = b * 9216 + g * 1152 + e;
            xn[idx]    = v;
            xn_bf[idx] = f2bf(v);
        }
    } else {
        int t = blockIdx.x - 768;                 // 0..2303
        int seg = t / 576;
        int idx = (t - seg * 576) * 128 + threadIdx.x;   // 0..73727 exactly
        const float* src = seg == 0 ? Wq : seg == 1 ? Wk : seg == 2 ? Wv : Wo;
        u16* dst = seg == 0 ? WqT : seg == 1 ? WkT : seg == 2 ? WvT : WoT;
        if (seg < 3) {
            int n = idx / 96, k2 = idx - n * 96;        // dst[n][k2]
            dst[idx] = f2bf(src[k2 * 768 + n]);
        } else {
            int n = idx / 768, k2 = idx - n * 768;      // dst[n][k2]
            dst[idx] = f2bf(src[k2 * 96 + n]);
        }
    }
}

// ---------------------------------------------------------------------------
// 2) Fused QKV + attention per (b,h).  grid 768, block 384 (6 waves).
//    wave w: q,k rows [16w,16w+16), v^T d-rows [16w,16w+16) via swapped
//    MFMA operands (V^T = Wv^T @ t^T) -> no transpose scatter.
//    Then QK^T -> causal softmax (registers) -> P@V; P reuses kb LDS.
// ---------------------------------------------------------------------------
__global__ __launch_bounds__(384) void fattn_kernel(
        const u16* __restrict__ xn_bf,
        const u16* __restrict__ WqT, const u16* __restrict__ WkT,
        const u16* __restrict__ WvT,
        const float* __restrict__ bq, const float* __restrict__ bk,
        const float* __restrict__ bv,
        u16* __restrict__ attn_out) {
    int b = blockIdx.x >> 3, h = blockIdx.x & 7;
    __shared__ __align__(16) u16 qb[96][104];
    __shared__ __align__(16) u16 kb[96][104];   // reused for P after QK^T
    __shared__ __align__(16) u16 vt[96][104];   // vt[d][s]

    int wave = threadIdx.x >> 6, lane = threadIdx.x & 63;
    int ln = lane & 15, quad = lane >> 4;
    int m0 = wave * 16;
    const u16* xb = xn_bf + b * 9216;
    const int hq = h * 96;

    // ---- QKV projection ----
    bf16x8 a[3], av[3];
    #pragma unroll
    for (int kt = 0; kt < 3; ++kt) {
        a[kt]  = *(const bf16x8*)(xb + (m0 + ln) * 96 + kt * 32 + quad * 8);
        av[kt] = *(const bf16x8*)(WvT + (hq + m0 + ln) * 96 + kt * 32 + quad * 8);
    }
    f32x4 aq[6] = {}, ak[6] = {}, avv[6] = {};
    #pragma unroll
    for (int kt = 0; kt < 3; ++kt) {
        #pragma unroll
        for (int nt = 0; nt < 6; ++nt) {
            bf16x8 bqf = *(const bf16x8*)(WqT + (hq + nt * 16 + ln) * 96 + kt * 32 + quad * 8);
            aq[nt] = MFMA16(a[kt], bqf, aq[nt]);
            bf16x8 bkf = *(const bf16x8*)(WkT + (hq + nt * 16 + ln) * 96 + kt * 32 + quad * 8);
            ak[nt] = MFMA16(a[kt], bkf, ak[nt]);
            bf16x8 bvf = *(const bf16x8*)(xb + (nt * 16 + ln) * 96 + kt * 32 + quad * 8);
            avv[nt] = MFMA16(av[kt], bvf, avv[nt]);
        }
    }
    float bvr[4];
    #pragma unroll
    for (int r = 0; r < 4; ++r) bvr[r] = bv[hq + m0 + quad * 4 + r];
    #pragma unroll
    for (int nt = 0; nt < 6; ++nt) {
        int col = nt * 16 + ln;
        float bqc = bq[hq + col], bkc = bk[hq + col];
        #pragma unroll
        for (int r = 0; r < 4; ++r) {
            int row = m0 + quad * 4 + r;
            qb[row][col] = f2bf(aq[nt][r] + bqc);
            kb[row][col] = f2bf(ak[nt][r] + bkc);
            vt[row][col] = f2bf(avv[nt][r] + bvr[r]);   // row=d, col=s
        }
    }
    __syncthreads();

    // ---- scores = QK^T ----
    f32x4 accs[6] = {};
    #pragma unroll
    for (int kt = 0; kt < 3; ++kt) {
        bf16x8 aa = *(const bf16x8*)(&qb[m0 + ln][kt * 32 + quad * 8]);
        #pragma unroll
        for (int nt = 0; nt < 6; ++nt) {
            bf16x8 bb = *(const bf16x8*)(&kb[nt * 16 + ln][kt * 32 + quad * 8]);
            accs[nt] = MFMA16(aa, bb, accs[nt]);
        }
    }

    // ---- causal softmax in registers; C layout row=quad*4+r, col=nt*16+ln
    const float scale = 0.10206207261596577f;   // 1/sqrt(96)
    float pout[4][6];
    #pragma unroll
    for (int r = 0; r < 4; ++r) {
        int row = m0 + quad * 4 + r;
        float vals[6], m = -1e30f;
        #pragma unroll
        for (int nt = 0; nt < 6; ++nt) {
            int col = nt * 16 + ln;
            float sv = accs[nt][r] * scale;
            vals[nt] = (col <= row) ? sv : -1e30f;
            m = fmaxf(m, vals[nt]);
        }
        #pragma unroll
        for (int off = 1; off < 16; off <<= 1) m = fmaxf(m, __shfl_xor(m, off));
        float sum = 0.f;
        #pragma unroll
        for (int nt = 0; nt < 6; ++nt) {
            float p = (vals[nt] > -1e29f) ? __expf(vals[nt] - m) : 0.f;
            pout[r][nt] = p; sum += p;
        }
        #pragma unroll
        for (int off = 1; off < 16; off <<= 1) sum += __shfl_xor(sum, off);
        float rinv = 1.0f / sum;
        #pragma unroll
        for (int nt = 0; nt < 6; ++nt) pout[r][nt] *= rinv;
    }
    __syncthreads();          // all waves done reading kb
    #pragma unroll
    for (int r = 0; r < 4; ++r)
        #pragma unroll
        for (int nt = 0; nt < 6; ++nt)
            kb[m0 + quad * 4 + r][nt * 16 + ln] = f2bf(pout[r][nt]);
    __syncthreads();          // P visible to all waves

    // ---- O = P @ V  (A = P rows, B = vt rows) ----
    f32x4 acco[6] = {};
    #pragma unroll
    for (int kt = 0; kt < 3; ++kt) {
        bf16x8 aa = *(const bf16x8*)(&kb[m0 + ln][kt * 32 + quad * 8]);
        #pragma unroll
        for (int nt = 0; nt < 6; ++nt) {
            bf16x8 bb = *(const bf16x8*)(&vt[nt * 16 + ln][kt * 32 + quad * 8]);
            acco[nt] = MFMA16(aa, bb, acco[nt]);
        }
    }
    const size_t obase = (size_t)b * 96 * DMODEL + hq;
    #pragma unroll
    for (int nt = 0; nt < 6; ++nt) {
        int d = nt * 16 + ln;
        #pragma unroll
        for (int r = 0; r < 4; ++r) {
            int row = m0 + quad * 4 + r;
            attn_out[obase + (size_t)row * DMODEL + d] = f2bf(acco[nt][r]);
        }
    }
}

// ---------------------------------------------------------------------------
// 3) Fused out-projection + broadcast residual.
//    grid 576 (16 proj rows each = one (j, k0..k0+16) tile), block 256.
//    Phase A: stage xn[:, j, :] (96x96 f32) to LDS (independent of MFMA).
//    Phase B: attn(16x768)@Wo(768x96) 4-way K-split MFMA -> red LDS.
//    Phase C: reduce + bias in-place into red[0] (each element owned by one
//             thread -> no extra barrier needed around the in-place update).
//    Phase D: stream out[i][j][k0+k][l] = proj[k][l] + xn[i][l] for all i,
//             nontemporal f32x4 stores (output is never re-read).
// ---------------------------------------------------------------------------
__global__ __launch_bounds__(256) void obcast_kernel(
        const u16* __restrict__ attn, const u16* __restrict__ WoT,
        const float* __restrict__ bo, const float* __restrict__ xn,
        float* __restrict__ out) {
    __shared__ __align__(16) float red[4][16][96];   // 24576 B
    __shared__ __align__(16) float xnt[96][96];      // 36864 B
    int wave = threadIdx.x >> 6, lane = threadIdx.x & 63;
    int ln = lane & 15, quad = lane >> 4;
    int m0 = blockIdx.x * 16;                 // proj rows [m0, m0+16)
    int j  = blockIdx.x / 6;                  // attention batch (16 | 96)
    int k0 = (blockIdx.x - j * 6) * 16;       // seq offset within batch j

    // Phase A: xn tile -> LDS (9 f32x4 per thread, coalesced)
    {
        const f32x4* xn4 = (const f32x4*)xn;
        f32x4* xt4 = (f32x4*)xnt;
        #pragma unroll
        for (int it = 0; it < 9; ++it) {
            int idx = threadIdx.x + it * 256;          // 0..2303
            int i = idx / 24, l4 = idx - i * 24;
            xt4[idx] = xn4[(size_t)(i * 96 + j) * 24 + l4];
        }
    }

    // Phase B: MFMA out-projection, K split across 4 waves
    int kw = wave * 192;
    f32x4 acc[6] = {};
    #pragma unroll
    for (int kt = 0; kt < 6; ++kt) {
        bf16x8 a = *(const bf16x8*)(attn + (size_t)(m0 + ln) * DMODEL + kw + kt * 32 + quad * 8);
        #pragma unroll
        for (int nt = 0; nt < 6; ++nt) {
            bf16x8 bb = *(const bf16x8*)(WoT + (nt * 16 + ln) * DMODEL + kw + kt * 32 + quad * 8);
            acc[nt] = MFMA16(a, bb, acc[nt]);
        }
    }
    #pragma unroll
    for (int nt = 0; nt < 6; ++nt)
        #pragma unroll
        for (int r = 0; r < 4; ++r)
            red[wave][quad * 4 + r][nt * 16 + ln] = acc[nt][r];
    __syncthreads();

    // Phase C: K-reduce + bias, in place into red[0]
    #pragma unroll
    for (int e = 0; e < 6; ++e) {
        int idx = threadIdx.x + e * 256;               // 0..1535
        int row = idx / 96, col = idx - row * 96;
        red[0][row][col] = red[0][row][col] + red[1][row][col] +
                           red[2][row][col] + red[3][row][col] + bo[col];
    }
    __syncthreads();

    // Phase D: stream the 96x16x96 output slab with residual add
    f32x4* out4 = (f32x4*)out;
    const f32x4* pt4 = (const f32x4*)red;              // red[0]: 16 x 24 f32x4
    const f32x4* xt4 = (const f32x4*)xnt;              // 96 x 24 f32x4
    #pragma unroll 4
    for (int it = 0; it < 144; ++it) {
        int idx = threadIdx.x + it * 256;              // 0..36863
        int i = idx / 384;                             // 384 f32x4 per i-slab
        int rem = idx - i * 384;
        int k = rem / 24, l4 = rem - k * 24;
        f32x4 pv = pt4[k * 24 + l4];
        f32x4 xv = xt4[i * 24 + l4];
        f32x4 rr = pv + xv;
        __builtin_nontemporal_store(rr,
            &out4[((size_t)(i * 96 + j) * 96 + (k0 + k)) * 24 + l4]);
    }
}

// ---------------------------------------------------------------------------
extern "C" void kernel_launch(void* const* d_in, const int* in_sizes, int n_in,
                              void* d_out, int out_size, void* d_ws, size_t ws_size,
                              hipStream_t stream) {
    const float* x     = (const float*)d_in[0];
    const float* Wq    = (const float*)d_in[1];
    const float* bq    = (const float*)d_in[2];
    const float* Wk    = (const float*)d_in[3];
    const float* bk    = (const float*)d_in[4];
    const float* Wv    = (const float*)d_in[5];
    const float* bv    = (const float*)d_in[6];
    const float* Wo    = (const float*)d_in[7];
    const float* bo    = (const float*)d_in[8];
    const float* gamma = (const float*)d_in[9];
    const float* beta  = (const float*)d_in[10];
    float* out = (float*)d_out;

    // workspace layout (bytes)
    char* ws = (char*)d_ws;
    float* xn_f = (float*)(ws + 0);                 //  3,538,944
    u16*  xn_b  = (u16*)(ws + 3538944);             //  1,769,472
    u16*  WqT   = (u16*)(ws + 5308416);             //    147,456
    u16*  WkT   = (u16*)(ws + 5455872);
    u16*  WvT   = (u16*)(ws + 5603328);
    u16*  WoT   = (u16*)(ws + 5750784);
    u16*  ab    = (u16*)(ws + 5898240);             // 14,155,776

    prep_kernel<<<dim3(3072), dim3(128), 0, stream>>>(
        x, gamma, beta, Wq, Wk, Wv, Wo, xn_f, xn_b, WqT, WkT, WvT, WoT);
    fattn_kernel<<<dim3(BATCH * NHEAD), dim3(384), 0, stream>>>(
        xn_b, WqT, WkT, WvT, bq, bk, bv, ab);
    obcast_kernel<<<dim3(576), dim3(256), 0, stream>>>(ab, WoT, bo, xn_f, out);
}

// Round 3
// 413.669 us; speedup vs baseline: 1.0395x; 1.0048x over previous
//
#include <hip/hip_runtime.h>
#include <hip/hip_bf16.h>

// Problem constants
#define BATCH 96
#define CH    96
#define SEQ   96
#define NHEAD 8
#define DK    96
#define DMODEL 768   // NHEAD*DK
#define GRP   8
#define EPSV  1e-5f

typedef __bf16 bf16x8 __attribute__((ext_vector_type(8)));
typedef float  f32x4  __attribute__((ext_vector_type(4)));
typedef unsigned short u16;

#define MFMA16(a, b, c) __builtin_amdgcn_mfma_f32_16x16x32_bf16((a), (b), (c), 0, 0, 0)

__device__ __forceinline__ u16 f2bf(float f) {
    union { float f; unsigned int u; } c; c.f = f;
    unsigned int u = c.u + 0x7fffu + ((c.u >> 16) & 1u);   // RNE
    return (u16)(u >> 16);
}

// ---------------------------------------------------------------------------
// 1) Prep: GroupNorm (blocks 0..767) + weight transpose/cast (blocks 768..3071)
//    gn: one block per (b,g), 128 threads x 9 elems (1152 per group).
//    wconv: seg 0..2: W (96,768)->WT (768,96); seg 3: Wo (768,96)->WoT (96,768)
// ---------------------------------------------------------------------------
__global__ __launch_bounds__(128) void prep_kernel(
        const float* __restrict__ x, const float* __restrict__ gamma,
        const float* __restrict__ beta,
        const float* __restrict__ Wq, const float* __restrict__ Wk,
        const float* __restrict__ Wv, const float* __restrict__ Wo,
        float* __restrict__ xn, u16* __restrict__ xn_bf,
        u16* __restrict__ WqT, u16* __restrict__ WkT,
        u16* __restrict__ WvT, u16* __restrict__ WoT) {
    if (blockIdx.x < 768) {
        int bg = blockIdx.x;
        int b = bg >> 3, g = bg & 7;
        const float* xp = x + b * 9216 + g * 1152;
        float vals[9];
        float s = 0.f, ss = 0.f;
        #pragma unroll
        for (int r = 0; r < 9; ++r) {
            float v = xp[threadIdx.x + 128 * r];
            vals[r] = v; s += v; ss += v * v;
        }
        #pragma unroll
        for (int off = 32; off > 0; off >>= 1) {
            s  += __shfl_down(s, off);
            ss += __shfl_down(ss, off);
        }
        __shared__ float red[4];
        if ((threadIdx.x & 63) == 0) {
            red[(threadIdx.x >> 6) * 2]     = s;
            red[(threadIdx.x >> 6) * 2 + 1] = ss;
        }
        __syncthreads();
        s = red[0] + red[2]; ss = red[1] + red[3];
        float mu   = s * (1.0f / 1152.0f);
        float var  = ss * (1.0f / 1152.0f) - mu * mu;
        float rsig = rsqrtf(var + EPSV);
        #pragma unroll
        for (int r = 0; r < 9; ++r) {
            int e = threadIdx.x + 128 * r;
            int c = g * 12 + e / 96;
            float v = (vals[r] - mu) * rsig * gamma[c] + beta[c];
            int idx = b * 9216 + g * 1152 + e;
            xn[idx]    = v;
            xn_bf[idx] = f2bf(v);
        }
    } else {
        int t = blockIdx.x - 768;                 // 0..2303
        int seg = t / 576;
        int idx = (t - seg * 576) * 128 + threadIdx.x;   // 0..73727 exactly
        const float* src = seg == 0 ? Wq : seg == 1 ? Wk : seg == 2 ? Wv : Wo;
        u16* dst = seg == 0 ? WqT : seg == 1 ? WkT : seg == 2 ? WvT : WoT;
        if (seg < 3) {
            int n = idx / 96, k2 = idx - n * 96;        // dst[n][k2]
            dst[idx] = f2bf(src[k2 * 768 + n]);
        } else {
            int n = idx / 768, k2 = idx - n * 768;      // dst[n][k2]
            dst[idx] = f2bf(src[k2 * 96 + n]);
        }
    }
}

// ---------------------------------------------------------------------------
// 2) Fused QKV + attention per (b,h).  grid 768, block 384 (6 waves).
//    wave w: q,k rows [16w,16w+16), v^T d-rows [16w,16w+16) via swapped
//    MFMA operands (V^T = Wv^T @ t^T) -> no transpose scatter.
//    Then QK^T -> causal softmax (registers) -> P@V; P reuses kb LDS.
// ---------------------------------------------------------------------------
__global__ __launch_bounds__(384) void fattn_kernel(
        const u16* __restrict__ xn_bf,
        const u16* __restrict__ WqT, const u16* __restrict__ WkT,
        const u16* __restrict__ WvT,
        const float* __restrict__ bq, const float* __restrict__ bk,
        const float* __restrict__ bv,
        u16* __restrict__ attn_out) {
    int b = blockIdx.x >> 3, h = blockIdx.x & 7;
    __shared__ __align__(16) u16 qb[96][104];
    __shared__ __align__(16) u16 kb[96][104];   // reused for P after QK^T
    __shared__ __align__(16) u16 vt[96][104];   // vt[d][s]

    int wave = threadIdx.x >> 6, lane = threadIdx.x & 63;
    int ln = lane & 15, quad = lane >> 4;
    int m0 = wave * 16;
    const u16* xb = xn_bf + b * 9216;
    const int hq = h * 96;

    // ---- QKV projection ----
    bf16x8 a[3], av[3];
    #pragma unroll
    for (int kt = 0; kt < 3; ++kt) {
        a[kt]  = *(const bf16x8*)(xb + (m0 + ln) * 96 + kt * 32 + quad * 8);
        av[kt] = *(const bf16x8*)(WvT + (hq + m0 + ln) * 96 + kt * 32 + quad * 8);
    }
    f32x4 aq[6] = {}, ak[6] = {}, avv[6] = {};
    #pragma unroll
    for (int kt = 0; kt < 3; ++kt) {
        #pragma unroll
        for (int nt = 0; nt < 6; ++nt) {
            bf16x8 bqf = *(const bf16x8*)(WqT + (hq + nt * 16 + ln) * 96 + kt * 32 + quad * 8);
            aq[nt] = MFMA16(a[kt], bqf, aq[nt]);
            bf16x8 bkf = *(const bf16x8*)(WkT + (hq + nt * 16 + ln) * 96 + kt * 32 + quad * 8);
            ak[nt] = MFMA16(a[kt], bkf, ak[nt]);
            bf16x8 bvf = *(const bf16x8*)(xb + (nt * 16 + ln) * 96 + kt * 32 + quad * 8);
            avv[nt] = MFMA16(av[kt], bvf, avv[nt]);
        }
    }
    float bvr[4];
    #pragma unroll
    for (int r = 0; r < 4; ++r) bvr[r] = bv[hq + m0 + quad * 4 + r];
    #pragma unroll
    for (int nt = 0; nt < 6; ++nt) {
        int col = nt * 16 + ln;
        float bqc = bq[hq + col], bkc = bk[hq + col];
        #pragma unroll
        for (int r = 0; r < 4; ++r) {
            int row = m0 + quad * 4 + r;
            qb[row][col] = f2bf(aq[nt][r] + bqc);
            kb[row][col] = f2bf(ak[nt][r] + bkc);
            vt[row][col] = f2bf(avv[nt][r] + bvr[r]);   // row=d, col=s
        }
    }
    __syncthreads();

    // ---- scores = QK^T ----
    f32x4 accs[6] = {};
    #pragma unroll
    for (int kt = 0; kt < 3; ++kt) {
        bf16x8 aa = *(const bf16x8*)(&qb[m0 + ln][kt * 32 + quad * 8]);
        #pragma unroll
        for (int nt = 0; nt < 6; ++nt) {
            bf16x8 bb = *(const bf16x8*)(&kb[nt * 16 + ln][kt * 32 + quad * 8]);
            accs[nt] = MFMA16(aa, bb, accs[nt]);
        }
    }

    // ---- causal softmax in registers; C layout row=quad*4+r, col=nt*16+ln
    const float scale = 0.10206207261596577f;   // 1/sqrt(96)
    float pout[4][6];
    #pragma unroll
    for (int r = 0; r < 4; ++r) {
        int row = m0 + quad * 4 + r;
        float vals[6], m = -1e30f;
        #pragma unroll
        for (int nt = 0; nt < 6; ++nt) {
            int col = nt * 16 + ln;
            float sv = accs[nt][r] * scale;
            vals[nt] = (col <= row) ? sv : -1e30f;
            m = fmaxf(m, vals[nt]);
        }
        #pragma unroll
        for (int off = 1; off < 16; off <<= 1) m = fmaxf(m, __shfl_xor(m, off));
        float sum = 0.f;
        #pragma unroll
        for (int nt = 0; nt < 6; ++nt) {
            float p = (vals[nt] > -1e29f) ? __expf(vals[nt] - m) : 0.f;
            pout[r][nt] = p; sum += p;
        }
        #pragma unroll
        for (int off = 1; off < 16; off <<= 1) sum += __shfl_xor(sum, off);
        float rinv = 1.0f / sum;
        #pragma unroll
        for (int nt = 0; nt < 6; ++nt) pout[r][nt] *= rinv;
    }
    __syncthreads();          // all waves done reading kb
    #pragma unroll
    for (int r = 0; r < 4; ++r)
        #pragma unroll
        for (int nt = 0; nt < 6; ++nt)
            kb[m0 + quad * 4 + r][nt * 16 + ln] = f2bf(pout[r][nt]);
    __syncthreads();          // P visible to all waves

    // ---- O = P @ V  (A = P rows, B = vt rows) ----
    f32x4 acco[6] = {};
    #pragma unroll
    for (int kt = 0; kt < 3; ++kt) {
        bf16x8 aa = *(const bf16x8*)(&kb[m0 + ln][kt * 32 + quad * 8]);
        #pragma unroll
        for (int nt = 0; nt < 6; ++nt) {
            bf16x8 bb = *(const bf16x8*)(&vt[nt * 16 + ln][kt * 32 + quad * 8]);
            acco[nt] = MFMA16(aa, bb, acco[nt]);
        }
    }
    const size_t obase = (size_t)b * 96 * DMODEL + hq;
    #pragma unroll
    for (int nt = 0; nt < 6; ++nt) {
        int d = nt * 16 + ln;
        #pragma unroll
        for (int r = 0; r < 4; ++r) {
            int row = m0 + quad * 4 + r;
            attn_out[obase + (size_t)row * DMODEL + d] = f2bf(acco[nt][r]);
        }
    }
}

// ---------------------------------------------------------------------------
// 3) Fused out-projection + broadcast residual, i-split 4 ways.
//    grid 2304 = (j 0..95, k0q 0..5, iq 0..3), block 384 (6 waves).
//    Each block: proj tile (16 rows x 96) for (j,k0) recomputed (cheap, WoT
//    is L2-resident), then streams the 24x16x96 output slab for its i-quarter.
//    Phase D has no divisions: thread <-> fixed (k,l4), one ptr bump per store.
// ---------------------------------------------------------------------------
__global__ __launch_bounds__(384) void obcast_kernel(
        const u16* __restrict__ attn, const u16* __restrict__ WoT,
        const float* __restrict__ bo, const float* __restrict__ xn,
        float* __restrict__ out) {
    __shared__ __align__(16) float red[6][16][96];   // 36864 B
    __shared__ __align__(16) float xnt[24][96];      //  9216 B
    int wave = threadIdx.x >> 6, lane = threadIdx.x & 63;
    int ln = lane & 15, quad = lane >> 4;

    int bid = blockIdx.x;
    int iq = bid & 3;                       // i quarter
    int jk = bid >> 2;                      // 0..575
    int j  = jk / 6;                        // attention batch
    int k0 = (jk - j * 6) * 16;             // seq offset within batch j
    int m0 = jk * 16;                       // proj rows [m0, m0+16)
    int i0 = iq * 24;

    // Phase A: xn[i0..i0+24)[j][:] -> LDS (576 f32x4; 384 + 192 threads)
    {
        const f32x4* xn4 = (const f32x4*)xn;
        f32x4* xt4 = (f32x4*)xnt;
        int idx = threadIdx.x;                     // 0..383
        int i = idx / 24, l4 = idx - i * 24;
        xt4[idx] = xn4[(size_t)((i0 + i) * 96 + j) * 24 + l4];
        if (threadIdx.x < 192) {
            int idx2 = threadIdx.x + 384;
            int i2 = idx2 / 24, l42 = idx2 - i2 * 24;
            xt4[idx2] = xn4[(size_t)((i0 + i2) * 96 + j) * 24 + l42];
        }
    }

    // Phase B: attn(16x768) @ Wo(768x96), K split 6 ways (128 per wave)
    int kw = wave * 128;
    f32x4 acc[6] = {};
    #pragma unroll
    for (int kt = 0; kt < 4; ++kt) {
        bf16x8 a = *(const bf16x8*)(attn + (size_t)(m0 + ln) * DMODEL + kw + kt * 32 + quad * 8);
        #pragma unroll
        for (int nt = 0; nt < 6; ++nt) {
            bf16x8 bb = *(const bf16x8*)(WoT + (nt * 16 + ln) * DMODEL + kw + kt * 32 + quad * 8);
            acc[nt] = MFMA16(a, bb, acc[nt]);
        }
    }
    #pragma unroll
    for (int nt = 0; nt < 6; ++nt)
        #pragma unroll
        for (int r = 0; r < 4; ++r)
            red[wave][quad * 4 + r][nt * 16 + ln] = acc[nt][r];
    __syncthreads();

    // Phase C: K-reduce + bias, in place into red[0] (owner-computes)
    #pragma unroll
    for (int e = 0; e < 4; ++e) {
        int idx = threadIdx.x + e * 384;           // 0..1535
        int row = idx / 96, col = idx - row * 96;
        red[0][row][col] = red[0][row][col] + red[1][row][col] +
                           red[2][row][col] + red[3][row][col] +
                           red[4][row][col] + red[5][row][col] + bo[col];
    }
    __syncthreads();

    // Phase D: stream the 24x16x96 output slab; no divisions in the loop
    f32x4* out4 = (f32x4*)out;
    const f32x4* pt4 = (const f32x4*)red;          // red[0]: 16 x 24 f32x4
    const f32x4* xt4 = (const f32x4*)xnt;          // 24 x 24 f32x4
    int k  = threadIdx.x / 24;                     // 384 = 16*24 exactly
    int l4 = threadIdx.x - k * 24;
    f32x4 pv = pt4[k * 24 + l4];
    size_t o = ((size_t)(i0 * 96 + j) * 96 + (k0 + k)) * 24 + l4;
    #pragma unroll
    for (int i = 0; i < 24; ++i) {
        f32x4 rr = pv + xt4[i * 24 + l4];
        __builtin_nontemporal_store(rr, &out4[o]);
        o += 221184;                               // 96*96*96/4 per i step
    }
}

// ---------------------------------------------------------------------------
extern "C" void kernel_launch(void* const* d_in, const int* in_sizes, int n_in,
                              void* d_out, int out_size, void* d_ws, size_t ws_size,
                              hipStream_t stream) {
    const float* x     = (const float*)d_in[0];
    const float* Wq    = (const float*)d_in[1];
    const float* bq    = (const float*)d_in[2];
    const float* Wk    = (const float*)d_in[3];
    const float* bk    = (const float*)d_in[4];
    const float* Wv    = (const float*)d_in[5];
    const float* bv    = (const float*)d_in[6];
    const float* Wo    = (const float*)d_in[7];
    const float* bo    = (const float*)d_in[8];
    const float* gamma = (const float*)d_in[9];
    const float* beta  = (const float*)d_in[10];
    float* out = (float*)d_out;

    // workspace layout (bytes)
    char* ws = (char*)d_ws;
    float* xn_f = (float*)(ws + 0);                 //  3,538,944
    u16*  xn_b  = (u16*)(ws + 3538944);             //  1,769,472
    u16*  WqT   = (u16*)(ws + 5308416);             //    147,456
    u16*  WkT   = (u16*)(ws + 5455872);
    u16*  WvT   = (u16*)(ws + 5603328);
    u16*  WoT   = (u16*)(ws + 5750784);
    u16*  ab    = (u16*)(ws + 5898240);             // 14,155,776

    prep_kernel<<<dim3(3072), dim3(128), 0, stream>>>(
        x, gamma, beta, Wq, Wk, Wv, Wo, xn_f, xn_b, WqT, WkT, WvT, WoT);
    fattn_kernel<<<dim3(BATCH * NHEAD), dim3(384), 0, stream>>>(
        xn_b, WqT, WkT, WvT, bq, bk, bv, ab);
    obcast_kernel<<<dim3(2304), dim3(384), 0, stream>>>(ab, WoT, bo, xn_f, out);
}

// Round 4
// 407.809 us; speedup vs baseline: 1.0544x; 1.0144x over previous
//
#include <hip/hip_runtime.h>
#include <hip/hip_bf16.h>

// Problem constants
#define BATCH 96
#define CH    96
#define SEQ   96
#define NHEAD 8
#define DK    96
#define DMODEL 768   // NHEAD*DK
#define GRP   8
#define EPSV  1e-5f

typedef __bf16 bf16x8 __attribute__((ext_vector_type(8)));
typedef float  f32x4  __attribute__((ext_vector_type(4)));
typedef unsigned short u16;

#define MFMA16(a, b, c) __builtin_amdgcn_mfma_f32_16x16x32_bf16((a), (b), (c), 0, 0, 0)

__device__ __forceinline__ u16 f2bf(float f) {
    union { float f; unsigned int u; } c; c.f = f;
    unsigned int u = c.u + 0x7fffu + ((c.u >> 16) & 1u);   // RNE
    return (u16)(u >> 16);
}

// ---------------------------------------------------------------------------
// 1) Prep: GroupNorm (blocks 0..767) + weight transpose/cast (blocks 768..3071)
//    gn: one block per (b,g), 128 threads x 9 elems (1152 per group).
//    wconv: source-linear iteration -> coalesced 4B reads; scattered 2B
//    stores are fire-and-forget (no latency stall on the read side).
// ---------------------------------------------------------------------------
__global__ __launch_bounds__(128) void prep_kernel(
        const float* __restrict__ x, const float* __restrict__ gamma,
        const float* __restrict__ beta,
        const float* __restrict__ Wq, const float* __restrict__ Wk,
        const float* __restrict__ Wv, const float* __restrict__ Wo,
        float* __restrict__ xn, u16* __restrict__ xn_bf,
        u16* __restrict__ WqT, u16* __restrict__ WkT,
        u16* __restrict__ WvT, u16* __restrict__ WoT) {
    if (blockIdx.x < 768) {
        int bg = blockIdx.x;
        int b = bg >> 3, g = bg & 7;
        const float* xp = x + b * 9216 + g * 1152;
        float vals[9];
        float s = 0.f, ss = 0.f;
        #pragma unroll
        for (int r = 0; r < 9; ++r) {
            float v = xp[threadIdx.x + 128 * r];
            vals[r] = v; s += v; ss += v * v;
        }
        #pragma unroll
        for (int off = 32; off > 0; off >>= 1) {
            s  += __shfl_down(s, off);
            ss += __shfl_down(ss, off);
        }
        __shared__ float red[4];
        if ((threadIdx.x & 63) == 0) {
            red[(threadIdx.x >> 6) * 2]     = s;
            red[(threadIdx.x >> 6) * 2 + 1] = ss;
        }
        __syncthreads();
        s = red[0] + red[2]; ss = red[1] + red[3];
        float mu   = s * (1.0f / 1152.0f);
        float var  = ss * (1.0f / 1152.0f) - mu * mu;
        float rsig = rsqrtf(var + EPSV);
        #pragma unroll
        for (int r = 0; r < 9; ++r) {
            int e = threadIdx.x + 128 * r;
            int c = g * 12 + e / 96;
            float v = (vals[r] - mu) * rsig * gamma[c] + beta[c];
            int idx = b * 9216 + g * 1152 + e;
            xn[idx]    = v;
            xn_bf[idx] = f2bf(v);
        }
    } else {
        int t = blockIdx.x - 768;                 // 0..2303
        int seg = t / 576;
        int idx = (t - seg * 576) * 128 + threadIdx.x;   // 0..73727 exactly
        const float* src = seg == 0 ? Wq : seg == 1 ? Wk : seg == 2 ? Wv : Wo;
        u16* dst = seg == 0 ? WqT : seg == 1 ? WkT : seg == 2 ? WvT : WoT;
        float v = src[idx];                       // coalesced read
        if (seg < 3) {
            int k2 = idx / 768, n = idx - k2 * 768;     // src (96,768)
            dst[n * 96 + k2] = f2bf(v);                 // WT (768,96)
        } else {
            int k2 = idx / 96, n = idx - k2 * 96;       // src (768,96)
            dst[n * 768 + k2] = f2bf(v);                // WoT (96,768)
        }
    }
}

// ---------------------------------------------------------------------------
// 2) Fused QKV + attention per (b,h).  grid 768, block 384 (6 waves).
//    QKV split into three sequential sub-GEMMs so each sub-phase's working
//    set (one 18KB weight slice + 18KB xb) fits L1 (32KB) instead of a 73KB
//    rotating set that thrashes.  Biases folded into accumulator init.
//    wave w: q,k rows [16w,16w+16), v^T d-rows [16w,16w+16) via swapped
//    MFMA operands -> no transpose scatter.  Then QK^T -> causal softmax
//    (registers) -> P@V; P reuses kb LDS.
// ---------------------------------------------------------------------------
__global__ __launch_bounds__(384) void fattn_kernel(
        const u16* __restrict__ xn_bf,
        const u16* __restrict__ WqT, const u16* __restrict__ WkT,
        const u16* __restrict__ WvT,
        const float* __restrict__ bq, const float* __restrict__ bk,
        const float* __restrict__ bv,
        u16* __restrict__ attn_out) {
    int b = blockIdx.x >> 3, h = blockIdx.x & 7;
    __shared__ __align__(16) u16 qb[96][104];
    __shared__ __align__(16) u16 kb[96][104];   // reused for P after QK^T
    __shared__ __align__(16) u16 vt[96][104];   // vt[d][s]

    int wave = threadIdx.x >> 6, lane = threadIdx.x & 63;
    int ln = lane & 15, quad = lane >> 4;
    int m0 = wave * 16;
    const u16* xb = xn_bf + b * 9216;
    const int hq = h * 96;

    // ---- A-operands (rows of t for q/k; rows of Wv^T for v^T) ----
    bf16x8 a[3], av[3];
    #pragma unroll
    for (int kt = 0; kt < 3; ++kt) {
        a[kt]  = *(const bf16x8*)(xb + (m0 + ln) * 96 + kt * 32 + quad * 8);
        av[kt] = *(const bf16x8*)(WvT + (hq + m0 + ln) * 96 + kt * 32 + quad * 8);
    }

    // ---- accumulators initialized with biases ----
    float bvr[4];
    #pragma unroll
    for (int r = 0; r < 4; ++r) bvr[r] = bv[hq + m0 + quad * 4 + r];
    f32x4 aq[6], ak[6], avv[6];
    #pragma unroll
    for (int nt = 0; nt < 6; ++nt) {
        float bqc = bq[hq + nt * 16 + ln];
        float bkc = bk[hq + nt * 16 + ln];
        aq[nt]  = f32x4{bqc, bqc, bqc, bqc};
        ak[nt]  = f32x4{bkc, bkc, bkc, bkc};
        avv[nt] = f32x4{bvr[0], bvr[1], bvr[2], bvr[3]};
    }

    // ---- Q sub-GEMM (working set: WqT slice 18KB + xb 18KB) ----
    #pragma unroll
    for (int kt = 0; kt < 3; ++kt)
        #pragma unroll
        for (int nt = 0; nt < 6; ++nt) {
            bf16x8 bqf = *(const bf16x8*)(WqT + (hq + nt * 16 + ln) * 96 + kt * 32 + quad * 8);
            aq[nt] = MFMA16(a[kt], bqf, aq[nt]);
        }
    // ---- K sub-GEMM ----
    #pragma unroll
    for (int kt = 0; kt < 3; ++kt)
        #pragma unroll
        for (int nt = 0; nt < 6; ++nt) {
            bf16x8 bkf = *(const bf16x8*)(WkT + (hq + nt * 16 + ln) * 96 + kt * 32 + quad * 8);
            ak[nt] = MFMA16(a[kt], bkf, ak[nt]);
        }
    // ---- V^T sub-GEMM (B = rows of t) ----
    #pragma unroll
    for (int kt = 0; kt < 3; ++kt)
        #pragma unroll
        for (int nt = 0; nt < 6; ++nt) {
            bf16x8 bvf = *(const bf16x8*)(xb + (nt * 16 + ln) * 96 + kt * 32 + quad * 8);
            avv[nt] = MFMA16(av[kt], bvf, avv[nt]);
        }

    #pragma unroll
    for (int nt = 0; nt < 6; ++nt) {
        int col = nt * 16 + ln;
        #pragma unroll
        for (int r = 0; r < 4; ++r) {
            int row = m0 + quad * 4 + r;
            qb[row][col] = f2bf(aq[nt][r]);
            kb[row][col] = f2bf(ak[nt][r]);
            vt[row][col] = f2bf(avv[nt][r]);   // row=d, col=s
        }
    }
    __syncthreads();

    // ---- scores = QK^T ----
    f32x4 accs[6] = {};
    #pragma unroll
    for (int kt = 0; kt < 3; ++kt) {
        bf16x8 aa = *(const bf16x8*)(&qb[m0 + ln][kt * 32 + quad * 8]);
        #pragma unroll
        for (int nt = 0; nt < 6; ++nt) {
            bf16x8 bb = *(const bf16x8*)(&kb[nt * 16 + ln][kt * 32 + quad * 8]);
            accs[nt] = MFMA16(aa, bb, accs[nt]);
        }
    }

    // ---- causal softmax in registers; C layout row=quad*4+r, col=nt*16+ln
    const float scale = 0.10206207261596577f;   // 1/sqrt(96)
    float pout[4][6];
    #pragma unroll
    for (int r = 0; r < 4; ++r) {
        int row = m0 + quad * 4 + r;
        float vals[6], m = -1e30f;
        #pragma unroll
        for (int nt = 0; nt < 6; ++nt) {
            int col = nt * 16 + ln;
            float sv = accs[nt][r] * scale;
            vals[nt] = (col <= row) ? sv : -1e30f;
            m = fmaxf(m, vals[nt]);
        }
        #pragma unroll
        for (int off = 1; off < 16; off <<= 1) m = fmaxf(m, __shfl_xor(m, off));
        float sum = 0.f;
        #pragma unroll
        for (int nt = 0; nt < 6; ++nt) {
            float p = (vals[nt] > -1e29f) ? __expf(vals[nt] - m) : 0.f;
            pout[r][nt] = p; sum += p;
        }
        #pragma unroll
        for (int off = 1; off < 16; off <<= 1) sum += __shfl_xor(sum, off);
        float rinv = 1.0f / sum;
        #pragma unroll
        for (int nt = 0; nt < 6; ++nt) pout[r][nt] *= rinv;
    }
    __syncthreads();          // all waves done reading kb
    #pragma unroll
    for (int r = 0; r < 4; ++r)
        #pragma unroll
        for (int nt = 0; nt < 6; ++nt)
            kb[m0 + quad * 4 + r][nt * 16 + ln] = f2bf(pout[r][nt]);
    __syncthreads();          // P visible to all waves

    // ---- O = P @ V  (A = P rows, B = vt rows) ----
    f32x4 acco[6] = {};
    #pragma unroll
    for (int kt = 0; kt < 3; ++kt) {
        bf16x8 aa = *(const bf16x8*)(&kb[m0 + ln][kt * 32 + quad * 8]);
        #pragma unroll
        for (int nt = 0; nt < 6; ++nt) {
            bf16x8 bb = *(const bf16x8*)(&vt[nt * 16 + ln][kt * 32 + quad * 8]);
            acco[nt] = MFMA16(aa, bb, acco[nt]);
        }
    }
    const size_t obase = (size_t)b * 96 * DMODEL + hq;
    #pragma unroll
    for (int nt = 0; nt < 6; ++nt) {
        int d = nt * 16 + ln;
        #pragma unroll
        for (int r = 0; r < 4; ++r) {
            int row = m0 + quad * 4 + r;
            attn_out[obase + (size_t)row * DMODEL + d] = f2bf(acco[nt][r]);
        }
    }
}

// ---------------------------------------------------------------------------
// 3) Fused out-projection + broadcast residual, i-split 4 ways.
//    grid 2304 = (j 0..95, k0q 0..5, iq 0..3), block 384 (6 waves).
//    Each block: proj tile (16 rows x 96) for (j,k0) recomputed (cheap, WoT
//    is L2-resident), then streams the 24x16x96 output slab for its i-quarter.
//    Phase D has no divisions: thread <-> fixed (k,l4), one ptr bump per store.
// ---------------------------------------------------------------------------
__global__ __launch_bounds__(384) void obcast_kernel(
        const u16* __restrict__ attn, const u16* __restrict__ WoT,
        const float* __restrict__ bo, const float* __restrict__ xn,
        float* __restrict__ out) {
    __shared__ __align__(16) float red[6][16][96];   // 36864 B
    __shared__ __align__(16) float xnt[24][96];      //  9216 B
    int wave = threadIdx.x >> 6, lane = threadIdx.x & 63;
    int ln = lane & 15, quad = lane >> 4;

    int bid = blockIdx.x;
    int iq = bid & 3;                       // i quarter
    int jk = bid >> 2;                      // 0..575
    int j  = jk / 6;                        // attention batch
    int k0 = (jk - j * 6) * 16;             // seq offset within batch j
    int m0 = jk * 16;                       // proj rows [m0, m0+16)
    int i0 = iq * 24;

    // Phase A: xn[i0..i0+24)[j][:] -> LDS (576 f32x4; 384 + 192 threads)
    {
        const f32x4* xn4 = (const f32x4*)xn;
        f32x4* xt4 = (f32x4*)xnt;
        int idx = threadIdx.x;                     // 0..383
        int i = idx / 24, l4 = idx - i * 24;
        xt4[idx] = xn4[(size_t)((i0 + i) * 96 + j) * 24 + l4];
        if (threadIdx.x < 192) {
            int idx2 = threadIdx.x + 384;
            int i2 = idx2 / 24, l42 = idx2 - i2 * 24;
            xt4[idx2] = xn4[(size_t)((i0 + i2) * 96 + j) * 24 + l42];
        }
    }

    // Phase B: attn(16x768) @ Wo(768x96), K split 6 ways (128 per wave)
    int kw = wave * 128;
    f32x4 acc[6] = {};
    #pragma unroll
    for (int kt = 0; kt < 4; ++kt) {
        bf16x8 a = *(const bf16x8*)(attn + (size_t)(m0 + ln) * DMODEL + kw + kt * 32 + quad * 8);
        #pragma unroll
        for (int nt = 0; nt < 6; ++nt) {
            bf16x8 bb = *(const bf16x8*)(WoT + (nt * 16 + ln) * DMODEL + kw + kt * 32 + quad * 8);
            acc[nt] = MFMA16(a, bb, acc[nt]);
        }
    }
    #pragma unroll
    for (int nt = 0; nt < 6; ++nt)
        #pragma unroll
        for (int r = 0; r < 4; ++r)
            red[wave][quad * 4 + r][nt * 16 + ln] = acc[nt][r];
    __syncthreads();

    // Phase C: K-reduce + bias, in place into red[0] (owner-computes)
    #pragma unroll
    for (int e = 0; e < 4; ++e) {
        int idx = threadIdx.x + e * 384;           // 0..1535
        int row = idx / 96, col = idx - row * 96;
        red[0][row][col] = red[0][row][col] + red[1][row][col] +
                           red[2][row][col] + red[3][row][col] +
                           red[4][row][col] + red[5][row][col] + bo[col];
    }
    __syncthreads();

    // Phase D: stream the 24x16x96 output slab; no divisions in the loop
    f32x4* out4 = (f32x4*)out;
    const f32x4* pt4 = (const f32x4*)red;          // red[0]: 16 x 24 f32x4
    const f32x4* xt4 = (const f32x4*)xnt;          // 24 x 24 f32x4
    int k  = threadIdx.x / 24;                     // 384 = 16*24 exactly
    int l4 = threadIdx.x - k * 24;
    f32x4 pv = pt4[k * 24 + l4];
    size_t o = ((size_t)(i0 * 96 + j) * 96 + (k0 + k)) * 24 + l4;
    #pragma unroll
    for (int i = 0; i < 24; ++i) {
        f32x4 rr = pv + xt4[i * 24 + l4];
        __builtin_nontemporal_store(rr, &out4[o]);
        o += 221184;                               // 96*96*96/4 per i step
    }
}

// ---------------------------------------------------------------------------
extern "C" void kernel_launch(void* const* d_in, const int* in_sizes, int n_in,
                              void* d_out, int out_size, void* d_ws, size_t ws_size,
                              hipStream_t stream) {
    const float* x     = (const float*)d_in[0];
    const float* Wq    = (const float*)d_in[1];
    const float* bq    = (const float*)d_in[2];
    const float* Wk    = (const float*)d_in[3];
    const float* bk    = (const float*)d_in[4];
    const float* Wv    = (const float*)d_in[5];
    const float* bv    = (const float*)d_in[6];
    const float* Wo    = (const float*)d_in[7];
    const float* bo    = (const float*)d_in[8];
    const float* gamma = (const float*)d_in[9];
    const float* beta  = (const float*)d_in[10];
    float* out = (float*)d_out;

    // workspace layout (bytes)
    char* ws = (char*)d_ws;
    float* xn_f = (float*)(ws + 0);                 //  3,538,944
    u16*  xn_b  = (u16*)(ws + 3538944);             //  1,769,472
    u16*  WqT   = (u16*)(ws + 5308416);             //    147,456
    u16*  WkT   = (u16*)(ws + 5455872);
    u16*  WvT   = (u16*)(ws + 5603328);
    u16*  WoT   = (u16*)(ws + 5750784);
    u16*  ab    = (u16*)(ws + 5898240);             // 14,155,776

    prep_kernel<<<dim3(3072), dim3(128), 0, stream>>>(
        x, gamma, beta, Wq, Wk, Wv, Wo, xn_f, xn_b, WqT, WkT, WvT, WoT);
    fattn_kernel<<<dim3(BATCH * NHEAD), dim3(384), 0, stream>>>(
        xn_b, WqT, WkT, WvT, bq, bk, bv, ab);
    obcast_kernel<<<dim3(2304), dim3(384), 0, stream>>>(ab, WoT, bo, xn_f, out);
}